// Round 4
// baseline (334.447 us; speedup 1.0000x reference)
//
#include <hip/hip_runtime.h>
#include <hip/hip_bf16.h>

#define B_  32
#define S_  512
#define D_  768
#define H_  12
#define HD_ 64
#define QKV_ELEMS (B_ * H_ * S_ * HD_)  // 12582912 per tensor

typedef __hip_bfloat16 bf16;
typedef short bf16x8_t __attribute__((ext_vector_type(8)));
typedef float f32x4_t  __attribute__((ext_vector_type(4)));

__device__ __forceinline__ float bf2f(bf16 x) { return __bfloat162float(x); }
__device__ __forceinline__ bf16  f2bf(float x) { return __float2bfloat16(x); }

__device__ __forceinline__ void gl_lds16(const short* g, short* l) {
    __builtin_amdgcn_global_load_lds(
        (const __attribute__((address_space(1))) void*)g,
        (__attribute__((address_space(3))) void*)l, 16, 0, 0);
}

// ---------------------------------------------------------------------------
// fp32 -> bf16 conversion (4 elems/thread)
// ---------------------------------------------------------------------------
__global__ __launch_bounds__(256) void f2bf_kernel(
    const float* __restrict__ in, unsigned short* __restrict__ out, int n4)
{
    int i = blockIdx.x * 256 + threadIdx.x;
    if (i >= n4) return;
    float4 v = reinterpret_cast<const float4*>(in)[i];
    ushort4 o;
    o.x = __bfloat16_as_ushort(f2bf(v.x));
    o.y = __bfloat16_as_ushort(f2bf(v.y));
    o.z = __bfloat16_as_ushort(f2bf(v.z));
    o.w = __bfloat16_as_ushort(f2bf(v.w));
    reinterpret_cast<ushort4*>(out)[i] = o;
}

// ---------------------------------------------------------------------------
// MFMA GEMM core, fragment-order LDS staging.
// C[128x128] = A[128xK] * B[128xK]^T.  256 threads = 4 waves.
// LDS layout: 16B chunks indexed [half(2)][ks32(2)][tile(4)][lane(64)]
//   group g = half*8 + ks32*4 + tile;  chunk addr = g*512 + lane*8 (shorts).
// Fragment reads are lane-contiguous b128 (conflict-free); the per-lane
// global address for global_load_lds supplies the scatter:
//   row = (g>>3)*64 + (g&3)*16 + l16,  col = ((g>>2)&1)*32 + quad*8.
// ---------------------------------------------------------------------------
#define GEMM_CORE(As, Bs, Aptr, Bptr, m0, n0, K)                               \
    const int t = threadIdx.x;                                                 \
    const int w = t >> 6, lane = t & 63;                                       \
    const int wr = w >> 1, wc = w & 1;                                         \
    const int quad = lane >> 4, l16 = lane & 15;                               \
    f32x4_t acc[4][4] = {};                                                    \
    int aoff[4], boff[4];                                                      \
    _Pragma("unroll")                                                          \
    for (int j = 0; j < 4; ++j) {                                              \
        int g = w * 4 + j;                                                     \
        int row = (g >> 3) * 64 + (g & 3) * 16 + l16;                          \
        int col = ((g >> 2) & 1) * 32 + quad * 8;                              \
        aoff[j] = ((m0) + row) * (K) + col;                                    \
        boff[j] = ((n0) + row) * (K) + col;                                    \
    }                                                                          \
    for (int k0 = 0; k0 < (K); k0 += 64) {                                     \
        __syncthreads();                                                       \
        _Pragma("unroll")                                                      \
        for (int j = 0; j < 4; ++j) {                                          \
            int g = w * 4 + j;                                                 \
            gl_lds16((Aptr) + aoff[j] + k0, &(As)[g * 512]);                   \
            gl_lds16((Bptr) + boff[j] + k0, &(Bs)[g * 512]);                   \
        }                                                                      \
        __syncthreads();                                                       \
        _Pragma("unroll")                                                      \
        for (int ks32 = 0; ks32 < 2; ++ks32) {                                 \
            bf16x8_t af[4], bf_[4];                                            \
            _Pragma("unroll")                                                  \
            for (int tm = 0; tm < 4; ++tm)                                     \
                af[tm] = *(const bf16x8_t*)&(As)[(wr * 8 + ks32 * 4 + tm) * 512 + lane * 8]; \
            _Pragma("unroll")                                                  \
            for (int tn = 0; tn < 4; ++tn)                                     \
                bf_[tn] = *(const bf16x8_t*)&(Bs)[(wc * 8 + ks32 * 4 + tn) * 512 + lane * 8]; \
            _Pragma("unroll")                                                  \
            for (int tm = 0; tm < 4; ++tm)                                     \
                _Pragma("unroll")                                              \
                for (int tn = 0; tn < 4; ++tn)                                 \
                    acc[tm][tn] = __builtin_amdgcn_mfma_f32_16x16x32_bf16(     \
                        af[tm], bf_[tn], acc[tm][tn], 0, 0, 0);                \
        }                                                                      \
    }

// ---------------------------------------------------------------------------
// Kernel 1: QKV projection -> q/k/v in [B,H,S,HD] bf16
// ---------------------------------------------------------------------------
__global__ __launch_bounds__(256) void qkv_gemm_mfma(
    const short* __restrict__ A, const short* __restrict__ W,
    const float* __restrict__ bias,
    bf16* __restrict__ Q, bf16* __restrict__ Kp, bf16* __restrict__ Vp)
{
    __shared__ short As[16 * 512];
    __shared__ short Bs[16 * 512];
    const int n0 = blockIdx.x * 128;
    const int m0 = blockIdx.y * 128;
    GEMM_CORE(As, Bs, A, W, m0, n0, 768)

    const int which = n0 / 768;
    const int h = ((n0 + wc * 64) % 768) >> 6;
    bf16* dst = (which == 0) ? Q : (which == 1) ? Kp : Vp;
    float bv[4];
#pragma unroll
    for (int tn = 0; tn < 4; ++tn) bv[tn] = bias[n0 + wc * 64 + tn * 16 + l16];
#pragma unroll
    for (int tm = 0; tm < 4; ++tm) {
#pragma unroll
        for (int r = 0; r < 4; ++r) {
            int m = m0 + wr * 64 + tm * 16 + quad * 4 + r;
            int b = m >> 9, s = m & 511;
            size_t rb = (((size_t)b * H_ + h) * S_ + s) * HD_;
#pragma unroll
            for (int tn = 0; tn < 4; ++tn)
                dst[rb + tn * 16 + l16] = f2bf(acc[tm][tn][r] + bv[tn]);
        }
    }
}

// ---------------------------------------------------------------------------
// Kernel 3: output projection, fp32 out
// ---------------------------------------------------------------------------
__global__ __launch_bounds__(256) void proj_gemm_mfma(
    const short* __restrict__ A, const short* __restrict__ W,
    const float* __restrict__ bias, float* __restrict__ out)
{
    __shared__ short As[16 * 512];
    __shared__ short Bs[16 * 512];
    const int n0 = blockIdx.x * 128;
    const int m0 = blockIdx.y * 128;
    GEMM_CORE(As, Bs, A, W, m0, n0, 768)

    float bv[4];
#pragma unroll
    for (int tn = 0; tn < 4; ++tn) bv[tn] = bias[n0 + wc * 64 + tn * 16 + l16];
#pragma unroll
    for (int tm = 0; tm < 4; ++tm) {
#pragma unroll
        for (int r = 0; r < 4; ++r) {
            int m = m0 + wr * 64 + tm * 16 + quad * 4 + r;
#pragma unroll
            for (int tn = 0; tn < 4; ++tn)
                out[(size_t)m * 768 + n0 + wc * 64 + tn * 16 + l16] =
                    acc[tm][tn][r] + bv[tn];
        }
    }
}

// ---------------------------------------------------------------------------
// Kernel 2: MFMA flash attention with fragment-order Q/K staging.
// Block = (b, h, 128-query tile); 4 waves, wave owns 32 queries.
// Q LDS: groups [w(4)][ks32(2)][tm(2)] = 16 groups * 1KB.
// K LDS: groups [ks32(2)][tn(4)]       =  8 groups * 1KB.
// Ps/Vt strides 68 shorts: writes/reads <=2-way (free).
// ---------------------------------------------------------------------------
#define QT 128
#define KT 64
#define PS 68
#define VS 68

__global__ __launch_bounds__(256, 3) void attn_mfma(
    const short* __restrict__ Qg, const short* __restrict__ Kg,
    const short* __restrict__ Vg, bf16* __restrict__ O)
{
    __shared__ short Qs[16 * 512];    // 16 KB
    __shared__ short Ks[8 * 512];     // 8 KB
    __shared__ short Vt[64 * VS];     // 8.5 KB  [dim][key]
    __shared__ short Ps[QT * PS];     // 17 KB

    const int t = threadIdx.x;
    const int w = t >> 6, lane = t & 63;
    const int quad = lane >> 4, l16 = lane & 15;
    const int qt = blockIdx.x & 3;
    const int bh = blockIdx.x >> 2;
    const int q0 = qt * QT;
    const size_t base = (size_t)bh * (S_ * HD_);

    // stage Q tile [128 x 64] once, fragment order
#pragma unroll
    for (int j = 0; j < 4; ++j) {           // j = ks32*2 + tm
        int tm = j & 1, ks32 = j >> 1;
        int row = q0 + w * 32 + tm * 16 + l16;
        int col = ks32 * 32 + quad * 8;
        gl_lds16(Qg + base + (size_t)row * 64 + col, &Qs[(w * 4 + j) * 512]);
    }

    int koff[2];
#pragma unroll
    for (int j = 0; j < 2; ++j) {
        int g2 = w * 2 + j;                 // g2 = ks32*4 + tn
        int tn = g2 & 3, ks32 = g2 >> 2;
        koff[j] = (tn * 16 + l16) * 64 + ks32 * 32 + quad * 8;
    }

    const int wq = w * 32;
    f32x4_t Oacc[2][4] = {};
    float lsum[2][4] = {};

    for (int kt = 0; kt < S_; kt += KT) {
        __syncthreads();
        // stage K tile [64 x 64], fragment order
#pragma unroll
        for (int j = 0; j < 2; ++j)
            gl_lds16(Kg + base + (size_t)kt * 64 + koff[j], &Ks[(w * 2 + j) * 512]);
        // stage V transposed: Vt[dim][key]
        {
            int k = lane, dg = w;
            const bf16x8_t* gv = (const bf16x8_t*)(Vg + base + (size_t)(kt + k) * 64 + dg * 16);
            bf16x8_t v0 = gv[0], v1 = gv[1];
#pragma unroll
            for (int i = 0; i < 8; ++i) {
                Vt[(dg * 16 + i) * VS + k]     = v0[i];
                Vt[(dg * 16 + 8 + i) * VS + k] = v1[i];
            }
        }
        __syncthreads();

        // QK^T: per-wave S tile [32 queries x 64 keys]
        f32x4_t sc[2][4] = {};
#pragma unroll
        for (int ks32 = 0; ks32 < 2; ++ks32) {
            bf16x8_t aq[2], bk[4];
#pragma unroll
            for (int tm = 0; tm < 2; ++tm)
                aq[tm] = *(const bf16x8_t*)&Qs[(w * 4 + ks32 * 2 + tm) * 512 + lane * 8];
#pragma unroll
            for (int tn = 0; tn < 4; ++tn)
                bk[tn] = *(const bf16x8_t*)&Ks[(ks32 * 4 + tn) * 512 + lane * 8];
#pragma unroll
            for (int tm = 0; tm < 2; ++tm)
#pragma unroll
                for (int tn = 0; tn < 4; ++tn)
                    sc[tm][tn] = __builtin_amdgcn_mfma_f32_16x16x32_bf16(
                        aq[tm], bk[tn], sc[tm][tn], 0, 0, 0);
        }

        // p = exp(s * 0.125); per-lane row partials; P -> LDS bf16
#pragma unroll
        for (int tm = 0; tm < 2; ++tm) {
#pragma unroll
            for (int r = 0; r < 4; ++r) {
                int row = wq + tm * 16 + quad * 4 + r;
                float rs = 0.f;
#pragma unroll
                for (int tn = 0; tn < 4; ++tn) {
                    float p = __expf(sc[tm][tn][r] * 0.125f);
                    rs += p;
                    Ps[row * PS + tn * 16 + l16] = (short)__bfloat16_as_ushort(f2bf(p));
                }
                lsum[tm][r] += rs;
            }
        }
        __syncthreads();

        // PV: O[32 x 64] per wave
#pragma unroll
        for (int ks = 0; ks < 64; ks += 32) {
            bf16x8_t ap[2], bv[4];
#pragma unroll
            for (int tm = 0; tm < 2; ++tm)
                ap[tm] = *(const bf16x8_t*)&Ps[(wq + tm * 16 + l16) * PS + ks + quad * 8];
#pragma unroll
            for (int tn = 0; tn < 4; ++tn)
                bv[tn] = *(const bf16x8_t*)&Vt[(tn * 16 + l16) * VS + ks + quad * 8];
#pragma unroll
            for (int tm = 0; tm < 2; ++tm)
#pragma unroll
                for (int tn = 0; tn < 4; ++tn)
                    Oacc[tm][tn] = __builtin_amdgcn_mfma_f32_16x16x32_bf16(
                        ap[tm], bv[tn], Oacc[tm][tn], 0, 0, 0);
        }
    }

    // reduce row sums across 16 col-lanes, normalize, store
    float linv[2][4];
#pragma unroll
    for (int tm = 0; tm < 2; ++tm)
#pragma unroll
        for (int r = 0; r < 4; ++r) {
            float v = lsum[tm][r];
            v += __shfl_xor(v, 1, 64);
            v += __shfl_xor(v, 2, 64);
            v += __shfl_xor(v, 4, 64);
            v += __shfl_xor(v, 8, 64);
            linv[tm][r] = 1.f / v;
        }
    const int b = bh / H_, h = bh % H_;
#pragma unroll
    for (int tm = 0; tm < 2; ++tm) {
#pragma unroll
        for (int r = 0; r < 4; ++r) {
            int row = q0 + wq + tm * 16 + quad * 4 + r;
            size_t ob = ((size_t)b * S_ + row) * D_ + h * HD_;
#pragma unroll
            for (int tn = 0; tn < 4; ++tn)
                O[ob + tn * 16 + l16] = f2bf(Oacc[tm][tn][r] * linv[tm][r]);
        }
    }
}

// ---------------------------------------------------------------------------
extern "C" void kernel_launch(void* const* d_in, const int* in_sizes, int n_in,
                              void* d_out, int out_size, void* d_ws, size_t ws_size,
                              hipStream_t stream) {
    const float* x      = (const float*)d_in[0];
    const float* qkv_w  = (const float*)d_in[1];
    const float* qkv_b  = (const float*)d_in[2];
    const float* proj_w = (const float*)d_in[3];
    const float* proj_b = (const float*)d_in[4];
    float* out = (float*)d_out;

    unsigned short* q     = (unsigned short*)d_ws;
    unsigned short* k     = q + QKV_ELEMS;
    unsigned short* v     = k + QKV_ELEMS;
    unsigned short* slot4 = v + QKV_ELEMS;          // x_bf, then attn-out
    unsigned short* wq    = slot4 + QKV_ELEMS;
    unsigned short* wp    = wq + 2304 * 768;

    f2bf_kernel<<<(16384 * 768 / 4 + 255) / 256, 256, 0, stream>>>(x, slot4, 16384 * 768 / 4);
    f2bf_kernel<<<(2304 * 768 / 4 + 255) / 256, 256, 0, stream>>>(qkv_w, wq, 2304 * 768 / 4);
    f2bf_kernel<<<(768 * 768 / 4 + 255) / 256, 256, 0, stream>>>(proj_w, wp, 768 * 768 / 4);

    qkv_gemm_mfma<<<dim3(18, 128), 256, 0, stream>>>(
        (const short*)slot4, (const short*)wq, qkv_b,
        (bf16*)q, (bf16*)k, (bf16*)v);

    attn_mfma<<<dim3(32 * 12 * 4), 256, 0, stream>>>(
        (const short*)q, (const short*)k, (const short*)v, (bf16*)slot4);

    proj_gemm_mfma<<<dim3(6, 128), 256, 0, stream>>>(
        (const short*)slot4, (const short*)wp, proj_b, out);
}

// Round 5
// 295.768 us; speedup vs baseline: 1.1308x; 1.1308x over previous
//
#include <hip/hip_runtime.h>
#include <hip/hip_bf16.h>

#define B_  32
#define S_  512
#define D_  768
#define H_  12
#define HD_ 64
#define QKV_ELEMS (B_ * H_ * S_ * HD_)  // 12582912 per tensor

typedef __hip_bfloat16 bf16;
typedef short bf16x8_t __attribute__((ext_vector_type(8)));
typedef float f32x4_t  __attribute__((ext_vector_type(4)));

__device__ __forceinline__ float bf2f(bf16 x) { return __bfloat162float(x); }
__device__ __forceinline__ bf16  f2bf(float x) { return __float2bfloat16(x); }

__device__ __forceinline__ void gl_lds16(const short* g, short* l) {
    __builtin_amdgcn_global_load_lds(
        (const __attribute__((address_space(1))) void*)g,
        (__attribute__((address_space(3))) void*)l, 16, 0, 0);
}

// ---------------------------------------------------------------------------
// fp32 -> bf16 conversion (4 elems/thread)
// ---------------------------------------------------------------------------
__global__ __launch_bounds__(256) void f2bf_kernel(
    const float* __restrict__ in, unsigned short* __restrict__ out, int n4)
{
    int i = blockIdx.x * 256 + threadIdx.x;
    if (i >= n4) return;
    float4 v = reinterpret_cast<const float4*>(in)[i];
    ushort4 o;
    o.x = __bfloat16_as_ushort(f2bf(v.x));
    o.y = __bfloat16_as_ushort(f2bf(v.y));
    o.z = __bfloat16_as_ushort(f2bf(v.z));
    o.w = __bfloat16_as_ushort(f2bf(v.w));
    reinterpret_cast<ushort4*>(out)[i] = o;
}

// ---------------------------------------------------------------------------
// MFMA GEMM core, m97-order LDS (coalesced 128B staging segments; the b128
// read "conflicts" are benign — measured r4), DOUBLE-BUFFERED:
//   prologue: load tile 0 into buf0
//   iter k:   barrier -> issue loads tile k+1 into buf (k+1)&1 -> MFMA on k
// The compiler's vmcnt(0) drain before the NEXT barrier waits on loads that
// had the whole compute phase in flight.  One barrier per K-iter.
// Buffers: 128x64 shorts = 8192 shorts each; As/Bs = 2 bufs = 32 KB each.
// ---------------------------------------------------------------------------
#define GEMM_CORE(As, Bs, Aptr, Bptr, m0, n0, K)                               \
    const int t = threadIdx.x;                                                 \
    const int w = t >> 6, lane = t & 63;                                       \
    const int wr = w >> 1, wc = w & 1;                                         \
    const int quad = lane >> 4, l16 = lane & 15;                               \
    f32x4_t acc[4][4] = {};                                                    \
    const int lrow = lane >> 3, lcol = (lane & 7) * 8;                         \
    _Pragma("unroll")                                                          \
    for (int j = 0; j < 4; ++j) {                                              \
        int R = j * 32 + w * 8;                                                \
        gl_lds16((Aptr) + (size_t)((m0) + R + lrow) * (K) + lcol, &(As)[R * 64]); \
        gl_lds16((Bptr) + (size_t)((n0) + R + lrow) * (K) + lcol, &(Bs)[R * 64]); \
    }                                                                          \
    for (int k0 = 0; k0 < (K); k0 += 64) {                                     \
        const int curo = ((k0 >> 6) & 1) * 8192;                               \
        __syncthreads();                                                       \
        if (k0 + 64 < (K)) {                                                   \
            const int nxo = curo ^ 8192;                                       \
            _Pragma("unroll")                                                  \
            for (int j = 0; j < 4; ++j) {                                      \
                int R = j * 32 + w * 8;                                        \
                gl_lds16((Aptr) + (size_t)((m0) + R + lrow) * (K) + k0 + 64 + lcol, \
                         &(As)[nxo + R * 64]);                                 \
                gl_lds16((Bptr) + (size_t)((n0) + R + lrow) * (K) + k0 + 64 + lcol, \
                         &(Bs)[nxo + R * 64]);                                 \
            }                                                                  \
        }                                                                      \
        _Pragma("unroll")                                                      \
        for (int ks = 0; ks < 64; ks += 32) {                                  \
            bf16x8_t af[4], bf_[4];                                            \
            _Pragma("unroll")                                                  \
            for (int tm = 0; tm < 4; ++tm)                                     \
                af[tm] = *(const bf16x8_t*)&(As)[curo + (wr * 64 + tm * 16 + l16) * 64 + ks + quad * 8]; \
            _Pragma("unroll")                                                  \
            for (int tn = 0; tn < 4; ++tn)                                     \
                bf_[tn] = *(const bf16x8_t*)&(Bs)[curo + (wc * 64 + tn * 16 + l16) * 64 + ks + quad * 8]; \
            _Pragma("unroll")                                                  \
            for (int tm = 0; tm < 4; ++tm)                                     \
                _Pragma("unroll")                                              \
                for (int tn = 0; tn < 4; ++tn)                                 \
                    acc[tm][tn] = __builtin_amdgcn_mfma_f32_16x16x32_bf16(     \
                        af[tm], bf_[tn], acc[tm][tn], 0, 0, 0);                \
        }                                                                      \
    }

// ---------------------------------------------------------------------------
// Kernel 1: QKV projection -> q/k/v in [B,H,S,HD] bf16
// ---------------------------------------------------------------------------
__global__ __launch_bounds__(256) void qkv_gemm_mfma(
    const short* __restrict__ A, const short* __restrict__ W,
    const float* __restrict__ bias,
    bf16* __restrict__ Q, bf16* __restrict__ Kp, bf16* __restrict__ Vp)
{
    __shared__ short As[2 * 128 * 64];   // 32 KB
    __shared__ short Bs[2 * 128 * 64];   // 32 KB
    const int n0 = blockIdx.x * 128;
    const int m0 = blockIdx.y * 128;
    GEMM_CORE(As, Bs, A, W, m0, n0, 768)

    const int which = n0 / 768;
    const int h = ((n0 + wc * 64) % 768) >> 6;
    bf16* dst = (which == 0) ? Q : (which == 1) ? Kp : Vp;
    float bv[4];
#pragma unroll
    for (int tn = 0; tn < 4; ++tn) bv[tn] = bias[n0 + wc * 64 + tn * 16 + l16];
#pragma unroll
    for (int tm = 0; tm < 4; ++tm) {
#pragma unroll
        for (int r = 0; r < 4; ++r) {
            int m = m0 + wr * 64 + tm * 16 + quad * 4 + r;
            int b = m >> 9, s = m & 511;
            size_t rb = (((size_t)b * H_ + h) * S_ + s) * HD_;
#pragma unroll
            for (int tn = 0; tn < 4; ++tn)
                dst[rb + tn * 16 + l16] = f2bf(acc[tm][tn][r] + bv[tn]);
        }
    }
}

// ---------------------------------------------------------------------------
// Kernel 3: output projection, fp32 out
// ---------------------------------------------------------------------------
__global__ __launch_bounds__(256) void proj_gemm_mfma(
    const short* __restrict__ A, const short* __restrict__ W,
    const float* __restrict__ bias, float* __restrict__ out)
{
    __shared__ short As[2 * 128 * 64];
    __shared__ short Bs[2 * 128 * 64];
    const int n0 = blockIdx.x * 128;
    const int m0 = blockIdx.y * 128;
    GEMM_CORE(As, Bs, A, W, m0, n0, 768)

    float bv[4];
#pragma unroll
    for (int tn = 0; tn < 4; ++tn) bv[tn] = bias[n0 + wc * 64 + tn * 16 + l16];
#pragma unroll
    for (int tm = 0; tm < 4; ++tm) {
#pragma unroll
        for (int r = 0; r < 4; ++r) {
            int m = m0 + wr * 64 + tm * 16 + quad * 4 + r;
#pragma unroll
            for (int tn = 0; tn < 4; ++tn)
                out[(size_t)m * 768 + n0 + wc * 64 + tn * 16 + l16] =
                    acc[tm][tn][r] + bv[tn];
        }
    }
}

// ---------------------------------------------------------------------------
// Kernel 2: MFMA flash attention (round-3 verified version: m97-order Q/K
// staging — coalesced global segments; benign b128 read conflicts).
// Block = (b, h, 128-query tile); 4 waves, wave owns 32 queries.
// ---------------------------------------------------------------------------
#define QT 128
#define KT 64
#define PS 68
#define VS 68

__global__ __launch_bounds__(256, 3) void attn_mfma(
    const short* __restrict__ Qg, const short* __restrict__ Kg,
    const short* __restrict__ Vg, bf16* __restrict__ O)
{
    __shared__ short Qs[QT * 64];     // 16 KB
    __shared__ short Ks[KT * 64];     // 8 KB
    __shared__ short Vt[64 * VS];     // 8.5 KB  [dim][key]
    __shared__ short Ps[QT * PS];     // 17 KB

    const int t = threadIdx.x;
    const int w = t >> 6, lane = t & 63;
    const int quad = lane >> 4, l16 = lane & 15;
    const int lrow = lane >> 3, lcol = (lane & 7) * 8;
    const int qt = blockIdx.x & 3;
    const int bh = blockIdx.x >> 2;
    const int q0 = qt * QT;
    const size_t base = (size_t)bh * (S_ * HD_);

    // stage Q tile [128 x 64] once
#pragma unroll
    for (int j = 0; j < 4; ++j) {
        int R = j * 32 + w * 8;
        gl_lds16(Qg + base + (size_t)(q0 + R + lrow) * 64 + lcol, &Qs[R * 64]);
    }

    const int wq = w * 32;
    f32x4_t Oacc[2][4] = {};
    float lsum[2][4] = {};

    for (int kt = 0; kt < S_; kt += KT) {
        __syncthreads();
        // stage K tile [64 x 64]
#pragma unroll
        for (int j = 0; j < 2; ++j) {
            int R = j * 32 + w * 8;
            gl_lds16(Kg + base + (size_t)(kt + R + lrow) * 64 + lcol, &Ks[R * 64]);
        }
        // stage V transposed: Vt[dim][key]
        {
            int k = lane, dg = w;
            const bf16x8_t* gv = (const bf16x8_t*)(Vg + base + (size_t)(kt + k) * 64 + dg * 16);
            bf16x8_t v0 = gv[0], v1 = gv[1];
#pragma unroll
            for (int i = 0; i < 8; ++i) {
                Vt[(dg * 16 + i) * VS + k]     = v0[i];
                Vt[(dg * 16 + 8 + i) * VS + k] = v1[i];
            }
        }
        __syncthreads();

        // QK^T: per-wave S tile [32 queries x 64 keys]
        f32x4_t sc[2][4] = {};
#pragma unroll
        for (int ks = 0; ks < 64; ks += 32) {
            bf16x8_t aq[2], bk[4];
#pragma unroll
            for (int tm = 0; tm < 2; ++tm)
                aq[tm] = *(const bf16x8_t*)&Qs[(wq + tm * 16 + l16) * 64 + ks + quad * 8];
#pragma unroll
            for (int tn = 0; tn < 4; ++tn)
                bk[tn] = *(const bf16x8_t*)&Ks[(tn * 16 + l16) * 64 + ks + quad * 8];
#pragma unroll
            for (int tm = 0; tm < 2; ++tm)
#pragma unroll
                for (int tn = 0; tn < 4; ++tn)
                    sc[tm][tn] = __builtin_amdgcn_mfma_f32_16x16x32_bf16(
                        aq[tm], bk[tn], sc[tm][tn], 0, 0, 0);
        }

        // p = exp(s * 0.125); per-lane row partials; P -> LDS bf16
#pragma unroll
        for (int tm = 0; tm < 2; ++tm) {
#pragma unroll
            for (int r = 0; r < 4; ++r) {
                int row = wq + tm * 16 + quad * 4 + r;
                float rs = 0.f;
#pragma unroll
                for (int tn = 0; tn < 4; ++tn) {
                    float p = __expf(sc[tm][tn][r] * 0.125f);
                    rs += p;
                    Ps[row * PS + tn * 16 + l16] = (short)__bfloat16_as_ushort(f2bf(p));
                }
                lsum[tm][r] += rs;
            }
        }
        __syncthreads();

        // PV: O[32 x 64] per wave
#pragma unroll
        for (int ks = 0; ks < 64; ks += 32) {
            bf16x8_t ap[2], bv[4];
#pragma unroll
            for (int tm = 0; tm < 2; ++tm)
                ap[tm] = *(const bf16x8_t*)&Ps[(wq + tm * 16 + l16) * PS + ks + quad * 8];
#pragma unroll
            for (int tn = 0; tn < 4; ++tn)
                bv[tn] = *(const bf16x8_t*)&Vt[(tn * 16 + l16) * VS + ks + quad * 8];
#pragma unroll
            for (int tm = 0; tm < 2; ++tm)
#pragma unroll
                for (int tn = 0; tn < 4; ++tn)
                    Oacc[tm][tn] = __builtin_amdgcn_mfma_f32_16x16x32_bf16(
                        ap[tm], bv[tn], Oacc[tm][tn], 0, 0, 0);
        }
    }

    // reduce row sums across 16 col-lanes, normalize, store
    float linv[2][4];
#pragma unroll
    for (int tm = 0; tm < 2; ++tm)
#pragma unroll
        for (int r = 0; r < 4; ++r) {
            float v = lsum[tm][r];
            v += __shfl_xor(v, 1, 64);
            v += __shfl_xor(v, 2, 64);
            v += __shfl_xor(v, 4, 64);
            v += __shfl_xor(v, 8, 64);
            linv[tm][r] = 1.f / v;
        }
    const int b = bh / H_, h = bh % H_;
#pragma unroll
    for (int tm = 0; tm < 2; ++tm) {
#pragma unroll
        for (int r = 0; r < 4; ++r) {
            int row = q0 + wq + tm * 16 + quad * 4 + r;
            size_t ob = ((size_t)b * S_ + row) * D_ + h * HD_;
#pragma unroll
            for (int tn = 0; tn < 4; ++tn)
                O[ob + tn * 16 + l16] = f2bf(Oacc[tm][tn][r] * linv[tm][r]);
        }
    }
}

// ---------------------------------------------------------------------------
extern "C" void kernel_launch(void* const* d_in, const int* in_sizes, int n_in,
                              void* d_out, int out_size, void* d_ws, size_t ws_size,
                              hipStream_t stream) {
    const float* x      = (const float*)d_in[0];
    const float* qkv_w  = (const float*)d_in[1];
    const float* qkv_b  = (const float*)d_in[2];
    const float* proj_w = (const float*)d_in[3];
    const float* proj_b = (const float*)d_in[4];
    float* out = (float*)d_out;

    unsigned short* q     = (unsigned short*)d_ws;
    unsigned short* k     = q + QKV_ELEMS;
    unsigned short* v     = k + QKV_ELEMS;
    unsigned short* slot4 = v + QKV_ELEMS;          // x_bf, then attn-out
    unsigned short* wq    = slot4 + QKV_ELEMS;
    unsigned short* wp    = wq + 2304 * 768;

    f2bf_kernel<<<(16384 * 768 / 4 + 255) / 256, 256, 0, stream>>>(x, slot4, 16384 * 768 / 4);
    f2bf_kernel<<<(2304 * 768 / 4 + 255) / 256, 256, 0, stream>>>(qkv_w, wq, 2304 * 768 / 4);
    f2bf_kernel<<<(768 * 768 / 4 + 255) / 256, 256, 0, stream>>>(proj_w, wp, 768 * 768 / 4);

    qkv_gemm_mfma<<<dim3(18, 128), 256, 0, stream>>>(
        (const short*)slot4, (const short*)wq, qkv_b,
        (bf16*)q, (bf16*)k, (bf16*)v);

    attn_mfma<<<dim3(32 * 12 * 4), 256, 0, stream>>>(
        (const short*)q, (const short*)k, (const short*)v, (bf16*)slot4);

    proj_gemm_mfma<<<dim3(6, 128), 256, 0, stream>>>(
        (const short*)slot4, (const short*)wp, proj_b, out);
}

// Round 6
// 278.049 us; speedup vs baseline: 1.2028x; 1.0637x over previous
//
#include <hip/hip_runtime.h>
#include <hip/hip_bf16.h>

#define B_  32
#define S_  512
#define D_  768
#define H_  12
#define HD_ 64
#define QKV_ELEMS (B_ * H_ * S_ * HD_)  // 12582912 per tensor

typedef __hip_bfloat16 bf16;
typedef short bf16x8_t __attribute__((ext_vector_type(8)));
typedef float f32x4_t  __attribute__((ext_vector_type(4)));

__device__ __forceinline__ float bf2f(bf16 x) { return __bfloat162float(x); }
__device__ __forceinline__ bf16  f2bf(float x) { return __float2bfloat16(x); }

__device__ __forceinline__ void gl_lds16(const short* g, short* l) {
    __builtin_amdgcn_global_load_lds(
        (const __attribute__((address_space(1))) void*)g,
        (__attribute__((address_space(3))) void*)l, 16, 0, 0);
}

// ---------------------------------------------------------------------------
// fp32 -> bf16 conversion (4 elems/thread)
// ---------------------------------------------------------------------------
__global__ __launch_bounds__(256) void f2bf_kernel(
    const float* __restrict__ in, unsigned short* __restrict__ out, int n4)
{
    int i = blockIdx.x * 256 + threadIdx.x;
    if (i >= n4) return;
    float4 v = reinterpret_cast<const float4*>(in)[i];
    ushort4 o;
    o.x = __bfloat16_as_ushort(f2bf(v.x));
    o.y = __bfloat16_as_ushort(f2bf(v.y));
    o.z = __bfloat16_as_ushort(f2bf(v.z));
    o.w = __bfloat16_as_ushort(f2bf(v.w));
    reinterpret_cast<ushort4*>(out)[i] = o;
}

// ---------------------------------------------------------------------------
// MFMA GEMM core: m97-order rows + XOR chunk swizzle + double buffer.
// LDS row r (128 B = 8 chunks of 16 B) stores global chunk c at slot
// c ^ (r & 7).  Staging keeps 128B-contiguous global segments (per-lane
// global addr permutes within the segment); fragment ds_read_b128 spreads
// 16 rows x 4 quads over all 32 banks at exactly 8 words/bank (conflict-
// free minimum).  Swizzle term is lane-constant: rows stay multiple-of-8.
//   prologue: load tile 0 into buf0
//   iter k:   barrier -> load tile k+1 into other buf -> MFMA on tile k
// ---------------------------------------------------------------------------
#define GEMM_CORE(As, Bs, Aptr, Bptr, m0, n0, K)                               \
    const int t = threadIdx.x;                                                 \
    const int w = t >> 6, lane = t & 63;                                       \
    const int wr = w >> 1, wc = w & 1;                                         \
    const int quad = lane >> 4, l16 = lane & 15;                               \
    f32x4_t acc[4][4] = {};                                                    \
    const int lrow = lane >> 3;                                                \
    const int scol = (((lane & 7) ^ (lrow & 7)) * 8);                          \
    _Pragma("unroll")                                                          \
    for (int j = 0; j < 4; ++j) {                                              \
        int R = j * 32 + w * 8;                                                \
        gl_lds16((Aptr) + (size_t)((m0) + R + lrow) * (K) + scol, &(As)[R * 64]); \
        gl_lds16((Bptr) + (size_t)((n0) + R + lrow) * (K) + scol, &(Bs)[R * 64]); \
    }                                                                          \
    for (int k0 = 0; k0 < (K); k0 += 64) {                                     \
        const int curo = ((k0 >> 6) & 1) * 8192;                               \
        __syncthreads();                                                       \
        if (k0 + 64 < (K)) {                                                   \
            const int nxo = curo ^ 8192;                                       \
            _Pragma("unroll")                                                  \
            for (int j = 0; j < 4; ++j) {                                      \
                int R = j * 32 + w * 8;                                        \
                gl_lds16((Aptr) + (size_t)((m0) + R + lrow) * (K) + k0 + 64 + scol, \
                         &(As)[nxo + R * 64]);                                 \
                gl_lds16((Bptr) + (size_t)((n0) + R + lrow) * (K) + k0 + 64 + scol, \
                         &(Bs)[nxo + R * 64]);                                 \
            }                                                                  \
        }                                                                      \
        _Pragma("unroll")                                                      \
        for (int ks = 0; ks < 64; ks += 32) {                                  \
            bf16x8_t af[4], bf_[4];                                            \
            _Pragma("unroll")                                                  \
            for (int tm = 0; tm < 4; ++tm)                                     \
                af[tm] = *(const bf16x8_t*)&(As)[curo + (wr * 64 + tm * 16 + l16) * 64 \
                        + ((((ks >> 3) + quad) ^ (l16 & 7)) * 8)];             \
            _Pragma("unroll")                                                  \
            for (int tn = 0; tn < 4; ++tn)                                     \
                bf_[tn] = *(const bf16x8_t*)&(Bs)[curo + (wc * 64 + tn * 16 + l16) * 64 \
                        + ((((ks >> 3) + quad) ^ (l16 & 7)) * 8)];             \
            _Pragma("unroll")                                                  \
            for (int tm = 0; tm < 4; ++tm)                                     \
                _Pragma("unroll")                                              \
                for (int tn = 0; tn < 4; ++tn)                                 \
                    acc[tm][tn] = __builtin_amdgcn_mfma_f32_16x16x32_bf16(     \
                        af[tm], bf_[tn], acc[tm][tn], 0, 0, 0);                \
        }                                                                      \
    }

// ---------------------------------------------------------------------------
// Kernel 1: QKV projection -> q/k/v in [B,H,S,HD] bf16
// ---------------------------------------------------------------------------
__global__ __launch_bounds__(256) void qkv_gemm_mfma(
    const short* __restrict__ A, const short* __restrict__ W,
    const float* __restrict__ bias,
    bf16* __restrict__ Q, bf16* __restrict__ Kp, bf16* __restrict__ Vp)
{
    __shared__ short As[2 * 128 * 64];   // 32 KB
    __shared__ short Bs[2 * 128 * 64];   // 32 KB
    const int n0 = blockIdx.x * 128;
    const int m0 = blockIdx.y * 128;
    GEMM_CORE(As, Bs, A, W, m0, n0, 768)

    const int which = n0 / 768;
    const int h = ((n0 + wc * 64) % 768) >> 6;
    bf16* dst = (which == 0) ? Q : (which == 1) ? Kp : Vp;
    float bv[4];
#pragma unroll
    for (int tn = 0; tn < 4; ++tn) bv[tn] = bias[n0 + wc * 64 + tn * 16 + l16];
#pragma unroll
    for (int tm = 0; tm < 4; ++tm) {
#pragma unroll
        for (int r = 0; r < 4; ++r) {
            int m = m0 + wr * 64 + tm * 16 + quad * 4 + r;
            int b = m >> 9, s = m & 511;
            size_t rb = (((size_t)b * H_ + h) * S_ + s) * HD_;
#pragma unroll
            for (int tn = 0; tn < 4; ++tn)
                dst[rb + tn * 16 + l16] = f2bf(acc[tm][tn][r] + bv[tn]);
        }
    }
}

// ---------------------------------------------------------------------------
// Kernel 3: output projection, fp32 out
// ---------------------------------------------------------------------------
__global__ __launch_bounds__(256) void proj_gemm_mfma(
    const short* __restrict__ A, const short* __restrict__ W,
    const float* __restrict__ bias, float* __restrict__ out)
{
    __shared__ short As[2 * 128 * 64];
    __shared__ short Bs[2 * 128 * 64];
    const int n0 = blockIdx.x * 128;
    const int m0 = blockIdx.y * 128;
    GEMM_CORE(As, Bs, A, W, m0, n0, 768)

    float bv[4];
#pragma unroll
    for (int tn = 0; tn < 4; ++tn) bv[tn] = bias[n0 + wc * 64 + tn * 16 + l16];
#pragma unroll
    for (int tm = 0; tm < 4; ++tm) {
#pragma unroll
        for (int r = 0; r < 4; ++r) {
            int m = m0 + wr * 64 + tm * 16 + quad * 4 + r;
#pragma unroll
            for (int tn = 0; tn < 4; ++tn)
                out[(size_t)m * 768 + n0 + wc * 64 + tn * 16 + l16] =
                    acc[tm][tn][r] + bv[tn];
        }
    }
}

// ---------------------------------------------------------------------------
// Kernel 2: MFMA flash attention, swizzled Q/K tiles.
// Block = (b, h, 128-query tile); 4 waves, wave owns 32 queries.
// Ps is wave-private (rows [w*32, w*32+32)) -> no barrier between Ps writes
// and PV reads (same-wave lgkmcnt dependency handled by compiler).
// ---------------------------------------------------------------------------
#define QT 128
#define KT 64
#define PS 68
#define VS 68

__global__ __launch_bounds__(256, 3) void attn_mfma(
    const short* __restrict__ Qg, const short* __restrict__ Kg,
    const short* __restrict__ Vg, bf16* __restrict__ O)
{
    __shared__ short Qs[QT * 64];     // 16 KB
    __shared__ short Ks[KT * 64];     // 8 KB
    __shared__ short Vt[64 * VS];     // 8.5 KB  [dim][key]
    __shared__ short Ps[QT * PS];     // 17 KB

    const int t = threadIdx.x;
    const int w = t >> 6, lane = t & 63;
    const int quad = lane >> 4, l16 = lane & 15;
    const int lrow = lane >> 3;
    const int scol = (((lane & 7) ^ (lrow & 7)) * 8);
    const int qt = blockIdx.x & 3;
    const int bh = blockIdx.x >> 2;
    const int q0 = qt * QT;
    const size_t base = (size_t)bh * (S_ * HD_);

    // stage Q tile [128 x 64] once (swizzled)
#pragma unroll
    for (int j = 0; j < 4; ++j) {
        int R = j * 32 + w * 8;
        gl_lds16(Qg + base + (size_t)(q0 + R + lrow) * 64 + scol, &Qs[R * 64]);
    }

    const int wq = w * 32;
    f32x4_t Oacc[2][4] = {};
    float lsum[2][4] = {};

    for (int kt = 0; kt < S_; kt += KT) {
        __syncthreads();
        // stage K tile [64 x 64] (swizzled)
#pragma unroll
        for (int j = 0; j < 2; ++j) {
            int R = j * 32 + w * 8;
            gl_lds16(Kg + base + (size_t)(kt + R + lrow) * 64 + scol, &Ks[R * 64]);
        }
        // stage V transposed: Vt[dim][key] (stride 68: reads/writes ~free)
        {
            int k = lane, dg = w;
            const bf16x8_t* gv = (const bf16x8_t*)(Vg + base + (size_t)(kt + k) * 64 + dg * 16);
            bf16x8_t v0 = gv[0], v1 = gv[1];
#pragma unroll
            for (int i = 0; i < 8; ++i) {
                Vt[(dg * 16 + i) * VS + k]     = v0[i];
                Vt[(dg * 16 + 8 + i) * VS + k] = v1[i];
            }
        }
        __syncthreads();

        // QK^T: per-wave S tile [32 queries x 64 keys]
        f32x4_t sc[2][4] = {};
#pragma unroll
        for (int ks = 0; ks < 64; ks += 32) {
            bf16x8_t aq[2], bk[4];
#pragma unroll
            for (int tm = 0; tm < 2; ++tm)
                aq[tm] = *(const bf16x8_t*)&Qs[(wq + tm * 16 + l16) * 64
                        + ((((ks >> 3) + quad) ^ (l16 & 7)) * 8)];
#pragma unroll
            for (int tn = 0; tn < 4; ++tn)
                bk[tn] = *(const bf16x8_t*)&Ks[(tn * 16 + l16) * 64
                        + ((((ks >> 3) + quad) ^ (l16 & 7)) * 8)];
#pragma unroll
            for (int tm = 0; tm < 2; ++tm)
#pragma unroll
                for (int tn = 0; tn < 4; ++tn)
                    sc[tm][tn] = __builtin_amdgcn_mfma_f32_16x16x32_bf16(
                        aq[tm], bk[tn], sc[tm][tn], 0, 0, 0);
        }

        // p = exp(s * 0.125); per-lane row partials; P -> LDS bf16
#pragma unroll
        for (int tm = 0; tm < 2; ++tm) {
#pragma unroll
            for (int r = 0; r < 4; ++r) {
                int row = wq + tm * 16 + quad * 4 + r;
                float rs = 0.f;
#pragma unroll
                for (int tn = 0; tn < 4; ++tn) {
                    float p = __expf(sc[tm][tn][r] * 0.125f);
                    rs += p;
                    Ps[row * PS + tn * 16 + l16] = (short)__bfloat16_as_ushort(f2bf(p));
                }
                lsum[tm][r] += rs;
            }
        }
        // no barrier: Ps rows [wq, wq+32) are written and read by this wave only

        // PV: O[32 x 64] per wave
#pragma unroll
        for (int ks = 0; ks < 64; ks += 32) {
            bf16x8_t ap[2], bv[4];
#pragma unroll
            for (int tm = 0; tm < 2; ++tm)
                ap[tm] = *(const bf16x8_t*)&Ps[(wq + tm * 16 + l16) * PS + ks + quad * 8];
#pragma unroll
            for (int tn = 0; tn < 4; ++tn)
                bv[tn] = *(const bf16x8_t*)&Vt[(tn * 16 + l16) * VS + ks + quad * 8];
#pragma unroll
            for (int tm = 0; tm < 2; ++tm)
#pragma unroll
                for (int tn = 0; tn < 4; ++tn)
                    Oacc[tm][tn] = __builtin_amdgcn_mfma_f32_16x16x32_bf16(
                        ap[tm], bv[tn], Oacc[tm][tn], 0, 0, 0);
        }
    }

    // reduce row sums across 16 col-lanes, normalize, store
    float linv[2][4];
#pragma unroll
    for (int tm = 0; tm < 2; ++tm)
#pragma unroll
        for (int r = 0; r < 4; ++r) {
            float v = lsum[tm][r];
            v += __shfl_xor(v, 1, 64);
            v += __shfl_xor(v, 2, 64);
            v += __shfl_xor(v, 4, 64);
            v += __shfl_xor(v, 8, 64);
            linv[tm][r] = 1.f / v;
        }
    const int b = bh / H_, h = bh % H_;
#pragma unroll
    for (int tm = 0; tm < 2; ++tm) {
#pragma unroll
        for (int r = 0; r < 4; ++r) {
            int row = q0 + wq + tm * 16 + quad * 4 + r;
            size_t ob = ((size_t)b * S_ + row) * D_ + h * HD_;
#pragma unroll
            for (int tn = 0; tn < 4; ++tn)
                O[ob + tn * 16 + l16] = f2bf(Oacc[tm][tn][r] * linv[tm][r]);
        }
    }
}

// ---------------------------------------------------------------------------
extern "C" void kernel_launch(void* const* d_in, const int* in_sizes, int n_in,
                              void* d_out, int out_size, void* d_ws, size_t ws_size,
                              hipStream_t stream) {
    const float* x      = (const float*)d_in[0];
    const float* qkv_w  = (const float*)d_in[1];
    const float* qkv_b  = (const float*)d_in[2];
    const float* proj_w = (const float*)d_in[3];
    const float* proj_b = (const float*)d_in[4];
    float* out = (float*)d_out;

    unsigned short* q     = (unsigned short*)d_ws;
    unsigned short* k     = q + QKV_ELEMS;
    unsigned short* v     = k + QKV_ELEMS;
    unsigned short* slot4 = v + QKV_ELEMS;          // x_bf, then attn-out
    unsigned short* wq    = slot4 + QKV_ELEMS;
    unsigned short* wp    = wq + 2304 * 768;

    f2bf_kernel<<<(16384 * 768 / 4 + 255) / 256, 256, 0, stream>>>(x, slot4, 16384 * 768 / 4);
    f2bf_kernel<<<(2304 * 768 / 4 + 255) / 256, 256, 0, stream>>>(qkv_w, wq, 2304 * 768 / 4);
    f2bf_kernel<<<(768 * 768 / 4 + 255) / 256, 256, 0, stream>>>(proj_w, wp, 768 * 768 / 4);

    qkv_gemm_mfma<<<dim3(18, 128), 256, 0, stream>>>(
        (const short*)slot4, (const short*)wq, qkv_b,
        (bf16*)q, (bf16*)k, (bf16*)v);

    attn_mfma<<<dim3(32 * 12 * 4), 256, 0, stream>>>(
        (const short*)q, (const short*)k, (const short*)v, (bf16*)slot4);

    proj_gemm_mfma<<<dim3(6, 128), 256, 0, stream>>>(
        (const short*)slot4, (const short*)wp, proj_b, out);
}